// Round 6
// baseline (328.890 us; speedup 1.0000x reference)
//
#include <hip/hip_runtime.h>
#include <hip/hip_bf16.h>
#include <hip/hip_fp16.h>

#define NN 50000
#define INCH 512
#define OUTCH 64
#define NTILES 3125       // 50000 / 16 (exact)
#define MAXD 48           // ELL slots per row; P(Poisson(16) > 48) ~ 5e-11 per row
#define GB 782            // gemm blocks: ceil(3125 tiles / 4 waves)
#define SCB 512           // scatter blocks per pass
#define ROWS_PER_PASS 12500   // NN/4: ELL slice = 12500*48*4 = 2.4 MB < 4 MB L2

typedef __attribute__((ext_vector_type(8))) short short8;
typedef __attribute__((ext_vector_type(4))) float floatx4;

__device__ __forceinline__ unsigned packbf2(float a, float b) {
    __hip_bfloat162 h = __float22bfloat162_rn(make_float2(a, b));  // v_cvt_pk_bf16_f32 RNE
    unsigned r;
    __builtin_memcpy(&r, &h, 4);
    return r;
}
__device__ __forceinline__ unsigned short f2bf(float f) {
    unsigned u = __float_as_uint(f);
    return (unsigned short)((u + 0x7FFFu + ((u >> 16) & 1u)) >> 16);  // RNE
}
__device__ __forceinline__ float bf2f(unsigned short u) {
    return __uint_as_float(((unsigned)u) << 16);
}

// ---------------- prep: zero deg + convert W fp32 [k][n] -> bf16 [n][k] ----------
__global__ __launch_bounds__(256) void prep_kernel(const float* __restrict__ W,
                                                   unsigned short* __restrict__ Wbf,
                                                   int* __restrict__ deg) {
    const int i = blockIdx.x * 256 + threadIdx.x;
    if (i < NN / 4)   // 12500 uint4 = 50000 ints exactly
        *reinterpret_cast<uint4*>(deg + i * 4) = uint4{0u, 0u, 0u, 0u};
    if (i < INCH * OUTCH) {
        const int k = i >> 6;          // W is [k][n], read coalesced
        const int n = i & 63;
        Wbf[n * INCH + k] = f2bf(W[i]);
    }
}

// ---------------- pure GEMM: feat[N,512] @ W -> x0 bf16 [N,64] ----------
// Barrier-free 16-row wave tiles; B-fragments from L2-resident Wbf; nt feat
// loads (single-use stream); LDS transpose epilogue for full-line stores.
__global__ __launch_bounds__(256, 4) void gemm_kernel(
        const float* __restrict__ A, const unsigned short* __restrict__ Wbf,
        unsigned short* __restrict__ C) {
    __shared__ unsigned short ldsT[4][16 * 64];   // 2 KB per wave
    const int t = threadIdx.x;
    const int lane = t & 63;
    const int wave = t >> 6;
    const int tile = blockIdx.x * 4 + wave;
    if (tile >= NTILES) return;
    const int rbase = tile * 16;
    const int frow = lane & 15;
    const int quad = lane >> 4;
    const float* Ap = A + (size_t)(rbase + frow) * INCH + quad * 8;
    const unsigned short* Bp = Wbf + frow * INCH + quad * 8;

    floatx4 acc[4] = {floatx4{0,0,0,0}, floatx4{0,0,0,0}, floatx4{0,0,0,0}, floatx4{0,0,0,0}};

#pragma unroll
    for (int c = 0; c < 16; ++c) {
        const floatx4 a0 = __builtin_nontemporal_load((const floatx4*)(Ap + c * 32));
        const floatx4 a1 = __builtin_nontemporal_load((const floatx4*)(Ap + c * 32 + 4));
        short8 bfr[4];
#pragma unroll
        for (int f = 0; f < 4; ++f)   // Wbf hot: normal cached loads
            bfr[f] = *(const short8*)(Bp + (size_t)f * 16 * INCH + c * 32);
        uint4 au;
        au.x = packbf2(a0[0], a0[1]);
        au.y = packbf2(a0[2], a0[3]);
        au.z = packbf2(a1[0], a1[1]);
        au.w = packbf2(a1[2], a1[3]);
        const short8 af = *(const short8*)&au;
#pragma unroll
        for (int f = 0; f < 4; ++f)
            acc[f] = __builtin_amdgcn_mfma_f32_16x16x32_bf16(af, bfr[f], acc[f], 0, 0, 0);
    }

    // C/D layout: col = f*16 + frow, row = quad*4 + reg   [m89]
    unsigned short* myT = ldsT[wave];
#pragma unroll
    for (int f = 0; f < 4; ++f)
#pragma unroll
        for (int reg = 0; reg < 4; ++reg)
            myT[(quad * 4 + reg) * 64 + f * 16 + frow] = f2bf(acc[f][reg]);
    // wave-local: ds ordering handled by lgkmcnt, no barrier needed
    unsigned short* Cw = C + (size_t)rbase * OUTCH;
#pragma unroll
    for (int it = 0; it < 2; ++it) {
        const short8 v = *(const short8*)&myT[it * 512 + lane * 8];
        __builtin_nontemporal_store(v, (short8*)(Cw + it * 512 + lane * 8));
    }
}

// ---------------- ELL build, one row-quarter per sequential launch ----------
// Pass owns rows [rowlo, rowlo+12500): its 2.4 MB ELL slice fits EVERY XCD's
// 4 MB L2 simultaneously (no block->XCD mapping assumption). Edge list is
// scanned fully each pass with nt (evict-first) loads so the stream doesn't
// evict the slice. Random 4B ELL stores hit L2 and write back whole lines
// once at pass end (~2.4 MB) instead of per-edge line churn to HBM.
__global__ __launch_bounds__(256) void scatter_pass(
        const int* __restrict__ rows, const int* __restrict__ cols,
        const float* __restrict__ vals, int* __restrict__ deg,
        unsigned* __restrict__ ell, int E_, int rowlo) {
    for (int e = blockIdx.x * 256 + threadIdx.x; e < E_; e += SCB * 256) {
        const int r = __builtin_nontemporal_load(rows + e);
        if ((unsigned)(r - rowlo) < (unsigned)ROWS_PER_PASS) {
            const int c = __builtin_nontemporal_load(cols + e);
            const float v = __builtin_nontemporal_load(vals + e);
            const int slot = atomicAdd(&deg[r], 1);
            if (slot < MAXD) {
                const unsigned short hv = __half_as_ushort(__float2half(v));
                ell[(size_t)r * MAXD + slot] = (unsigned)c | ((unsigned)hv << 16);
            }
        }
    }
}

// ---------------- SpMM over ELL, one 32-channel half per sequential launch ----
// Channels are independent in x <- A x, so each launch gathers ONLY from a
// 3.2 MB half-table (bytes [chbase*2, chbase*2+64) of each 128B row) that is
// L2-resident on every XCD during that launch — no XCD-mapping gamble.
// 16 edge-slots x 4 lanes x 8 ch; all 3 ELL rounds loaded up-front (nt) with
// sentinel masking; wave-uniform round skips; shfl reduce over slots.
template <bool LAST>
__global__ __launch_bounds__(256) void spmm_half(const int* __restrict__ deg,
                                                 const unsigned* __restrict__ ell,
                                                 const unsigned short* __restrict__ xin,
                                                 void* __restrict__ xout_,
                                                 const float* __restrict__ bias,
                                                 int chbase) {
    const int t = threadIdx.x;
    const int lane = t & 63;
    const int eslot = lane >> 2;              // 0..15: edge slot
    const int cg = lane & 3;                  // channel group: 8 ch each
    const int row = blockIdx.x * 4 + (t >> 6);   // grid = 12500
    int d = deg[row];
    d = d < MAXD ? d : MAXD;                  // defensive clamp
    const unsigned* ebase = ell + (size_t)row * MAXD;

    unsigned p0 = __builtin_nontemporal_load(ebase + eslot);
    unsigned p1 = __builtin_nontemporal_load(ebase + eslot + 16);
    unsigned p2 = __builtin_nontemporal_load(ebase + eslot + 32);
    if (eslot >= d)      p0 = 0u;             // col 0, val 0 -> contributes 0
    if (eslot + 16 >= d) p1 = 0u;
    if (eslot + 32 >= d) p2 = 0u;

    const unsigned short* xh = xin + chbase + cg * 8;
    float acc[8] = {0.f, 0.f, 0.f, 0.f, 0.f, 0.f, 0.f, 0.f};

    auto gath = [&](unsigned P) {
        // reused access: normal cached load (half-table L2-resident)
        const short8 xv = *(const short8*)(xh + (size_t)(P & 0xFFFFu) * OUTCH);
        const float v = __half2float(__ushort_as_half((unsigned short)(P >> 16)));
#pragma unroll
        for (int j = 0; j < 8; ++j)
            acc[j] = fmaf(v, bf2f((unsigned short)xv[j]), acc[j]);
    };
    if (d > 0)  gath(p0);
    if (d > 16) gath(p1);
    if (d > 32) gath(p2);

    // reduce across the 16 edge-slots (lane bits 2..5)
#pragma unroll
    for (int j = 0; j < 8; ++j) {
        acc[j] += __shfl_xor(acc[j], 4, 64);
        acc[j] += __shfl_xor(acc[j], 8, 64);
        acc[j] += __shfl_xor(acc[j], 16, 64);
        acc[j] += __shfl_xor(acc[j], 32, 64);
    }

    if (eslot == 0) {
        const int chb = chbase + cg * 8;
        if (LAST) {
            float* op = (float*)xout_ + (size_t)row * OUTCH + chb;
            const floatx4 b0 = *(const floatx4*)(bias + chb);
            const floatx4 b1 = *(const floatx4*)(bias + chb + 4);
            floatx4 o0, o1;
            o0[0] = acc[0] + b0[0]; o0[1] = acc[1] + b0[1];
            o0[2] = acc[2] + b0[2]; o0[3] = acc[3] + b0[3];
            o1[0] = acc[4] + b1[0]; o1[1] = acc[5] + b1[1];
            o1[2] = acc[6] + b1[2]; o1[3] = acc[7] + b1[3];
            __builtin_nontemporal_store(o0, (floatx4*)op);
            __builtin_nontemporal_store(o1, (floatx4*)(op + 4));
        } else {
            unsigned short* op = (unsigned short*)xout_ + (size_t)row * OUTCH + chb;
            short8 o;
#pragma unroll
            for (int j = 0; j < 8; ++j) o[j] = (short)f2bf(acc[j]);
            *(short8*)op = o;
        }
    }
}

extern "C" void kernel_launch(void* const* d_in, const int* in_sizes, int n_in,
                              void* d_out, int out_size, void* d_ws, size_t ws_size,
                              hipStream_t stream) {
    const int*   adj   = (const int*)d_in[0];     // [2, E]
    const float* avals = (const float*)d_in[1];   // [E]
    const float* feat  = (const float*)d_in[2];   // [N, 512]
    const float* W     = (const float*)d_in[3];   // [512, 64]
    const float* bias  = (const float*)d_in[4];   // [64]
    float* out = (float*)d_out;

    const int E_ = in_sizes[1];
    const int* rows = adj;
    const int* cols = adj + E_;

    // workspace layout (16B-aligned segments), total ~22.7 MB
    unsigned short* x0  = (unsigned short*)d_ws;            // N*64 bf16 (6.4 MB)
    unsigned short* x1  = x0 + (size_t)NN * OUTCH;          // N*64 bf16 (6.4 MB)
    unsigned short* Wbf = x1 + (size_t)NN * OUTCH;          // 64*512 bf16 (64 KB)
    unsigned* ell = (unsigned*)(Wbf + (size_t)OUTCH * INCH);// N*MAXD u32 (9.6 MB)
    int* deg = (int*)(ell + (size_t)NN * MAXD);             // N int (200 KB)

    // ---- prep: zero deg + convert W to bf16 [n][k] ----
    prep_kernel<<<128, 256, 0, stream>>>(W, Wbf, deg);

    // ---- dense projection (bf16 MFMA) ----
    gemm_kernel<<<GB, 256, 0, stream>>>(feat, Wbf, x0);

    // ---- ELL build: 4 sequential row-quarter passes (L2-resident slices) ----
    for (int p = 0; p < 4; ++p)
        scatter_pass<<<SCB, 256, 0, stream>>>(rows, cols, avals, deg, ell, E_,
                                              p * ROWS_PER_PASS);

    // ---- two SpMM hops, each as two 32-channel half launches ----
    spmm_half<false><<<NN / 4, 256, 0, stream>>>(deg, ell, x0, x1, nullptr, 0);
    spmm_half<false><<<NN / 4, 256, 0, stream>>>(deg, ell, x0, x1, nullptr, 32);
    spmm_half<true><<<NN / 4, 256, 0, stream>>>(deg, ell, x1, out, bias, 0);
    spmm_half<true><<<NN / 4, 256, 0, stream>>>(deg, ell, x1, out, bias, 32);
}

// Round 7
// 291.585 us; speedup vs baseline: 1.1279x; 1.1279x over previous
//
#include <hip/hip_runtime.h>
#include <hip/hip_bf16.h>
#include <hip/hip_fp16.h>

#define NN 50000
#define INCH 512
#define OUTCH 64
#define NTILES 3125       // 50000 / 16 (exact)
#define MAXDH 32          // ELL slots per row per col-side; Poisson(8) tail @32 ~1e-12
#define COLSPLIT 25000    // col-range split: each side's gather table = 3.2 MB < 4 MB L2
#define GB 782            // gemm blocks: ceil(3125 tiles / 4 waves)
#define SB 512            // scatter blocks appended after gemm blocks

typedef __attribute__((ext_vector_type(8))) short short8;
typedef __attribute__((ext_vector_type(4))) float floatx4;
typedef __attribute__((ext_vector_type(4))) unsigned short ushortx4;

__device__ __forceinline__ unsigned packbf2(float a, float b) {
    __hip_bfloat162 h = __float22bfloat162_rn(make_float2(a, b));  // v_cvt_pk_bf16_f32 RNE
    unsigned r;
    __builtin_memcpy(&r, &h, 4);
    return r;
}
__device__ __forceinline__ unsigned short f2bf(float f) {
    unsigned u = __float_as_uint(f);
    return (unsigned short)((u + 0x7FFFu + ((u >> 16) & 1u)) >> 16);  // RNE
}
__device__ __forceinline__ float bf2f(unsigned short u) {
    return __uint_as_float(((unsigned)u) << 16);
}

// ---------------- prep: zero deg_lo/deg_hi + convert W fp32 [k][n] -> bf16 [n][k] -------
__global__ __launch_bounds__(256) void prep_kernel(const float* __restrict__ W,
                                                   unsigned short* __restrict__ Wbf,
                                                   int* __restrict__ degs) {
    const int i = blockIdx.x * 256 + threadIdx.x;
    if (i < (2 * NN) / 4)   // deg_lo + deg_hi contiguous: 100000 ints = 25000 uint4
        *reinterpret_cast<uint4*>(degs + i * 4) = uint4{0u, 0u, 0u, 0u};
    if (i < INCH * OUTCH) {
        const int k = i >> 6;          // W is [k][n], read coalesced
        const int n = i & 63;
        Wbf[n * INCH + k] = f2bf(W[i]);
    }
}

// ---------------- fused: [blocks 0..GB) gemm | [GB..GB+SB) dual-ELL scatter -----------
// gemm: barrier-free 16-row wave tiles, B from L2-resident Wbf, nt feat loads.
// scatter: edges partitioned by col-range into ell_lo (col<25000) / ell_hi.
__global__ __launch_bounds__(256, 4) void fused_gemm_scatter(
        const float* __restrict__ A, const unsigned short* __restrict__ Wbf,
        unsigned short* __restrict__ C,
        const int* __restrict__ rows, const int* __restrict__ cols,
        const float* __restrict__ vals, int* __restrict__ deg_lo,
        int* __restrict__ deg_hi, unsigned* __restrict__ ell_lo,
        unsigned* __restrict__ ell_hi, int E_) {
    __shared__ unsigned short ldsT[4][16 * 64];   // 2 KB per wave, 8 KB total
    const int t = threadIdx.x;

    if (blockIdx.x >= GB) {
        // ---------- scatter: route each edge to its col-side ELL ----------
        for (int e = (blockIdx.x - GB) * 256 + t; e < E_; e += SB * 256) {
            const int r = __builtin_nontemporal_load(rows + e);
            const int c = __builtin_nontemporal_load(cols + e);
            const float v = __builtin_nontemporal_load(vals + e);
            const int hi = (c >= COLSPLIT);
            int* dg = hi ? deg_hi : deg_lo;
            unsigned* el = hi ? ell_hi : ell_lo;
            const int slot = atomicAdd(&dg[r], 1);
            if (slot < MAXDH) {
                const unsigned short hv = __half_as_ushort(__float2half(v));
                el[(size_t)r * MAXDH + slot] = (unsigned)c | ((unsigned)hv << 16);
            }
        }
        return;
    }

    // ---------- gemm part ----------
    const int lane = t & 63;
    const int wave = t >> 6;
    const int tile = blockIdx.x * 4 + wave;
    if (tile >= NTILES) return;
    const int rbase = tile * 16;
    const int frow = lane & 15;
    const int quad = lane >> 4;
    const float* Ap = A + (size_t)(rbase + frow) * INCH + quad * 8;
    const unsigned short* Bp = Wbf + frow * INCH + quad * 8;

    floatx4 acc[4] = {floatx4{0,0,0,0}, floatx4{0,0,0,0}, floatx4{0,0,0,0}, floatx4{0,0,0,0}};

#pragma unroll
    for (int c = 0; c < 16; ++c) {
        const floatx4 a0 = __builtin_nontemporal_load((const floatx4*)(Ap + c * 32));
        const floatx4 a1 = __builtin_nontemporal_load((const floatx4*)(Ap + c * 32 + 4));
        short8 bfr[4];
#pragma unroll
        for (int f = 0; f < 4; ++f)   // Wbf hot: normal cached loads
            bfr[f] = *(const short8*)(Bp + (size_t)f * 16 * INCH + c * 32);
        uint4 au;
        au.x = packbf2(a0[0], a0[1]);
        au.y = packbf2(a0[2], a0[3]);
        au.z = packbf2(a1[0], a1[1]);
        au.w = packbf2(a1[2], a1[3]);
        const short8 af = *(const short8*)&au;
#pragma unroll
        for (int f = 0; f < 4; ++f)
            acc[f] = __builtin_amdgcn_mfma_f32_16x16x32_bf16(af, bfr[f], acc[f], 0, 0, 0);
    }

    // C/D layout: col = f*16 + frow, row = quad*4 + reg   [m89]
    unsigned short* myT = ldsT[wave];
#pragma unroll
    for (int f = 0; f < 4; ++f)
#pragma unroll
        for (int reg = 0; reg < 4; ++reg)
            myT[(quad * 4 + reg) * 64 + f * 16 + frow] = f2bf(acc[f][reg]);
    // wave-local: ds ordering handled by lgkmcnt, no barrier needed
    unsigned short* Cw = C + (size_t)rbase * OUTCH;
#pragma unroll
    for (int it = 0; it < 2; ++it) {
        const short8 v = *(const short8*)&myT[it * 512 + lane * 8];
        __builtin_nontemporal_store(v, (short8*)(Cw + it * 512 + lane * 8));
    }
}

// ---------------- SpMM col-side phase: wave per row, 4 eslots x 16 ch-lanes ----------
// Each phase gathers ONLY from a contiguous 3.2 MB x-range (cols [0,25000) or
// [25000,50000)) that is simultaneously L2-resident on every XCD — no
// block->XCD mapping assumption. Full 128 B rows gathered (no channel split),
// each edge's ELL entry read exactly once per hop. Streams (ELL, partial,
// outputs) are nt so they don't evict the gather table.
// MODE 0: write fp32 partial.  MODE 1: +partial -> bf16 x1.  MODE 2: +partial
// +bias -> fp32 out.
template <int MODE>
__global__ __launch_bounds__(256) void spmm_phase(
        const int* __restrict__ degs, const unsigned* __restrict__ ells,
        const unsigned short* __restrict__ xin, float* __restrict__ partial,
        void* __restrict__ xout_, const float* __restrict__ bias) {
    const int t = threadIdx.x;
    const int lane = t & 63;
    const int eslot = lane >> 4;              // 0..3: edge slot group
    const int cl = lane & 15;                 // channel lane: 4 ch each
    const int row = blockIdx.x * 4 + (t >> 6);   // grid = 12500, NN exact
    int d = degs[row];
    d = d < MAXDH ? d : MAXDH;                // defensive clamp
    const unsigned* eb = ells + (size_t)row * MAXDH;

    // all 8 slot-words per eslot loaded up-front (nt), sentinel-masked
    unsigned p[8];
#pragma unroll
    for (int j = 0; j < 8; ++j)
        p[j] = __builtin_nontemporal_load(eb + eslot + 4 * j);
#pragma unroll
    for (int j = 0; j < 8; ++j)
        if (eslot + 4 * j >= d) p[j] = 0u;    // col 0, val 0 -> contributes 0

    float a0 = 0.f, a1 = 0.f, a2 = 0.f, a3 = 0.f;
#pragma unroll
    for (int j = 0; j < 8; ++j) {
        if (d > 4 * j) {                      // wave-uniform round skip
            const unsigned P = p[j];
            const ushortx4 xv = *(const ushortx4*)(xin + (size_t)(P & 0xFFFFu) * OUTCH + cl * 4);
            const float v = __half2float(__ushort_as_half((unsigned short)(P >> 16)));
            a0 = fmaf(v, bf2f(xv[0]), a0);
            a1 = fmaf(v, bf2f(xv[1]), a1);
            a2 = fmaf(v, bf2f(xv[2]), a2);
            a3 = fmaf(v, bf2f(xv[3]), a3);
        }
    }

    // reduce across the 4 edge-slot groups (lane bits 4,5)
    a0 += __shfl_xor(a0, 16, 64); a1 += __shfl_xor(a1, 16, 64);
    a2 += __shfl_xor(a2, 16, 64); a3 += __shfl_xor(a3, 16, 64);
    a0 += __shfl_xor(a0, 32, 64); a1 += __shfl_xor(a1, 32, 64);
    a2 += __shfl_xor(a2, 32, 64); a3 += __shfl_xor(a3, 32, 64);

    if (eslot == 0) {
        const int chb = cl * 4;
        if (MODE == 0) {
            floatx4 o = {a0, a1, a2, a3};
            __builtin_nontemporal_store(o, (floatx4*)(partial + (size_t)row * OUTCH + chb));
        } else {
            const floatx4 pp = __builtin_nontemporal_load(
                (const floatx4*)(partial + (size_t)row * OUTCH + chb));
            a0 += pp[0]; a1 += pp[1]; a2 += pp[2]; a3 += pp[3];
            if (MODE == 1) {
                ushortx4 o = {f2bf(a0), f2bf(a1), f2bf(a2), f2bf(a3)};
                __builtin_nontemporal_store(
                    o, (ushortx4*)((unsigned short*)xout_ + (size_t)row * OUTCH + chb));
            } else {
                const floatx4 bv = *(const floatx4*)(bias + chb);
                floatx4 o = {a0 + bv[0], a1 + bv[1], a2 + bv[2], a3 + bv[3]};
                __builtin_nontemporal_store(
                    o, (floatx4*)((float*)xout_ + (size_t)row * OUTCH + chb));
            }
        }
    }
}

extern "C" void kernel_launch(void* const* d_in, const int* in_sizes, int n_in,
                              void* d_out, int out_size, void* d_ws, size_t ws_size,
                              hipStream_t stream) {
    const int*   adj   = (const int*)d_in[0];     // [2, E]
    const float* avals = (const float*)d_in[1];   // [E]
    const float* feat  = (const float*)d_in[2];   // [N, 512]
    const float* W     = (const float*)d_in[3];   // [512, 64]
    const float* bias  = (const float*)d_in[4];   // [64]
    float* out = (float*)d_out;

    const int E_ = in_sizes[1];
    const int* rows = adj;
    const int* cols = adj + E_;

    // workspace layout (16B-aligned segments), total ~38.9 MB
    unsigned short* x0  = (unsigned short*)d_ws;             // N*64 bf16 (6.4 MB)
    unsigned short* x1  = x0 + (size_t)NN * OUTCH;           // N*64 bf16 (6.4 MB)
    unsigned short* Wbf = x1 + (size_t)NN * OUTCH;           // 64*512 bf16 (64 KB)
    unsigned* ell_lo = (unsigned*)(Wbf + (size_t)OUTCH * INCH); // N*32 u32 (6.4 MB)
    unsigned* ell_hi = ell_lo + (size_t)NN * MAXDH;          // N*32 u32 (6.4 MB)
    int* deg_lo = (int*)(ell_hi + (size_t)NN * MAXDH);       // N int (200 KB)
    int* deg_hi = deg_lo + NN;                               // N int (200 KB)
    float* partial = (float*)(deg_hi + NN);                  // N*64 fp32 (12.8 MB)

    // ---- prep: zero both deg arrays + convert W to bf16 [n][k] ----
    prep_kernel<<<128, 256, 0, stream>>>(W, Wbf, deg_lo);

    // ---- fused: dense projection (bf16 MFMA) + dual-ELL scatter ----
    fused_gemm_scatter<<<GB + SB, 256, 0, stream>>>(feat, Wbf, x0, rows, cols, avals,
                                                    deg_lo, deg_hi, ell_lo, ell_hi, E_);

    // ---- hop 1: lo-cols -> partial, hi-cols + partial -> x1 (bf16) ----
    spmm_phase<0><<<NN / 4, 256, 0, stream>>>(deg_lo, ell_lo, x0, partial, nullptr, nullptr);
    spmm_phase<1><<<NN / 4, 256, 0, stream>>>(deg_hi, ell_hi, x0, partial, x1, nullptr);

    // ---- hop 2: lo-cols -> partial, hi-cols + partial + bias -> out (fp32) ----
    spmm_phase<0><<<NN / 4, 256, 0, stream>>>(deg_lo, ell_lo, x1, partial, nullptr, nullptr);
    spmm_phase<2><<<NN / 4, 256, 0, stream>>>(deg_hi, ell_hi, x1, partial, out, bias);
}

// Round 8
// 253.369 us; speedup vs baseline: 1.2981x; 1.1508x over previous
//
#include <hip/hip_runtime.h>
#include <hip/hip_bf16.h>
#include <hip/hip_fp16.h>

#define NN 50000
#define INCH 512
#define OUTCH 64
#define NTILES 3125       // 50000 / 16 (exact)
#define MAXD 48           // ELL slots per row; P(Poisson(16) > 48) ~ 5e-11 per row
#define GB 782            // gemm blocks: ceil(3125 tiles / 4 waves)
#define SB 512            // scatter blocks appended after gemm blocks

typedef __attribute__((ext_vector_type(8))) short short8;
typedef __attribute__((ext_vector_type(4))) float floatx4;

__device__ __forceinline__ unsigned packbf2(float a, float b) {
    __hip_bfloat162 h = __float22bfloat162_rn(make_float2(a, b));  // v_cvt_pk_bf16_f32 RNE
    unsigned r;
    __builtin_memcpy(&r, &h, 4);
    return r;
}
__device__ __forceinline__ unsigned short f2bf(float f) {
    unsigned u = __float_as_uint(f);
    return (unsigned short)((u + 0x7FFFu + ((u >> 16) & 1u)) >> 16);  // RNE
}
__device__ __forceinline__ float bf2f(unsigned short u) {
    return __uint_as_float(((unsigned)u) << 16);
}

// ---------------- prep: zero deg + convert W fp32 [k][n] -> bf16 [n][k] ----------
__global__ __launch_bounds__(256) void prep_kernel(const float* __restrict__ W,
                                                   unsigned short* __restrict__ Wbf,
                                                   int* __restrict__ deg) {
    const int i = blockIdx.x * 256 + threadIdx.x;
    if (i < NN / 4)   // 12500 uint4 = 50000 ints exactly
        *reinterpret_cast<uint4*>(deg + i * 4) = uint4{0u, 0u, 0u, 0u};
    if (i < INCH * OUTCH) {
        const int k = i >> 6;          // W is [k][n], read coalesced
        const int n = i & 63;
        Wbf[n * INCH + k] = f2bf(W[i]);
    }
}

// ---------------- fused: [blocks 0..GB) gemm | [GB..GB+SB) ELL scatter ----------------
// All scatter traffic is non-temporal: edge-list loads are single-use streams,
// and the random 4B ELL stores use nt to request NO-ALLOCATE (write-through to
// L3) — avoiding the 64B write-allocate fill + dirty-line writeback per edge
// that produced the ~55+54 MB HBM churn in every cached-store variant.
__global__ __launch_bounds__(256, 4) void fused_gemm_scatter(
        const float* __restrict__ A, const unsigned short* __restrict__ Wbf,
        unsigned short* __restrict__ C,
        const int* __restrict__ rows, const int* __restrict__ cols,
        const float* __restrict__ vals, int* __restrict__ deg,
        unsigned* __restrict__ ell, int E_) {
    __shared__ unsigned short ldsT[4][16 * 64];   // 2 KB per wave, 8 KB total
    const int t = threadIdx.x;

    if (blockIdx.x >= GB) {
        // ---------- scatter part (single pass, nt stores) ----------
        for (int e = (blockIdx.x - GB) * 256 + t; e < E_; e += SB * 256) {
            const int r = __builtin_nontemporal_load(rows + e);
            const int c = __builtin_nontemporal_load(cols + e);
            const float v = __builtin_nontemporal_load(vals + e);
            const int slot = atomicAdd(&deg[r], 1);
            if (slot < MAXD) {
                const unsigned short hv = __half_as_ushort(__float2half(v));
                __builtin_nontemporal_store((unsigned)c | ((unsigned)hv << 16),
                                            &ell[(size_t)r * MAXD + slot]);
            }
        }
        return;
    }

    // ---------- gemm part ----------
    const int lane = t & 63;
    const int wave = t >> 6;
    const int tile = blockIdx.x * 4 + wave;
    if (tile >= NTILES) return;
    const int rbase = tile * 16;
    const int frow = lane & 15;
    const int quad = lane >> 4;
    const float* Ap = A + (size_t)(rbase + frow) * INCH + quad * 8;
    const unsigned short* Bp = Wbf + frow * INCH + quad * 8;

    floatx4 acc[4] = {floatx4{0,0,0,0}, floatx4{0,0,0,0}, floatx4{0,0,0,0}, floatx4{0,0,0,0}};

#pragma unroll
    for (int c = 0; c < 16; ++c) {
        const floatx4 a0 = __builtin_nontemporal_load((const floatx4*)(Ap + c * 32));
        const floatx4 a1 = __builtin_nontemporal_load((const floatx4*)(Ap + c * 32 + 4));
        short8 bfr[4];
#pragma unroll
        for (int f = 0; f < 4; ++f)   // Wbf hot: normal cached loads
            bfr[f] = *(const short8*)(Bp + (size_t)f * 16 * INCH + c * 32);
        uint4 au;
        au.x = packbf2(a0[0], a0[1]);
        au.y = packbf2(a0[2], a0[3]);
        au.z = packbf2(a1[0], a1[1]);
        au.w = packbf2(a1[2], a1[3]);
        const short8 af = *(const short8*)&au;
#pragma unroll
        for (int f = 0; f < 4; ++f)
            acc[f] = __builtin_amdgcn_mfma_f32_16x16x32_bf16(af, bfr[f], acc[f], 0, 0, 0);
    }

    // C/D layout: col = f*16 + frow, row = quad*4 + reg   [m89]
    unsigned short* myT = ldsT[wave];
#pragma unroll
    for (int f = 0; f < 4; ++f)
#pragma unroll
        for (int reg = 0; reg < 4; ++reg)
            myT[(quad * 4 + reg) * 64 + f * 16 + frow] = f2bf(acc[f][reg]);
    // wave-local: ds ordering handled by lgkmcnt, no barrier needed
    unsigned short* Cw = C + (size_t)rbase * OUTCH;
#pragma unroll
    for (int it = 0; it < 2; ++it) {
        const short8 v = *(const short8*)&myT[it * 512 + lane * 8];
        __builtin_nontemporal_store(v, (short8*)(Cw + it * 512 + lane * 8));
    }
}

// ---------------- SpMM over ELL: wave per row, 8 edge-slots x 8 ch-lanes ----------
// Full 128B row gathered per edge (minimum random-line count: 2 lines/edge).
// All 6 ELL slot-words pre-loaded (nt) with sentinel masking -> up to 8 gathers
// in flight per wave; wave-uniform round skips (typ. d~16 -> 2 of 6 rounds).
template <bool LAST>
__global__ __launch_bounds__(256) void spmm_full(const int* __restrict__ deg,
                                                 const unsigned* __restrict__ ell,
                                                 const unsigned short* __restrict__ xin,
                                                 void* __restrict__ xout_,
                                                 const float* __restrict__ bias) {
    const int t = threadIdx.x;
    const int lane = t & 63;
    const int eslot = lane >> 3;              // 0..7: edge slot group
    const int cg = lane & 7;                  // channel group: 8 ch (16B) each
    const int row = blockIdx.x * 4 + (t >> 6);   // grid = 12500, NN exact
    int d = deg[row];
    d = d < MAXD ? d : MAXD;                  // defensive clamp
    const unsigned* eb = ell + (size_t)row * MAXD;

    // 6 slot-words per eslot group, loaded up-front (nt), sentinel-masked
    unsigned p[6];
#pragma unroll
    for (int j = 0; j < 6; ++j)
        p[j] = __builtin_nontemporal_load(eb + eslot + 8 * j);
#pragma unroll
    for (int j = 0; j < 6; ++j)
        if (eslot + 8 * j >= d) p[j] = 0u;    // col 0, val 0 -> contributes 0

    const unsigned short* xh = xin + cg * 8;
    float acc[8] = {0.f, 0.f, 0.f, 0.f, 0.f, 0.f, 0.f, 0.f};

#pragma unroll
    for (int j = 0; j < 6; ++j) {
        if (d > 8 * j) {                      // wave-uniform round skip
            const unsigned P = p[j];
            const short8 xv = *(const short8*)(xh + (size_t)(P & 0xFFFFu) * OUTCH);
            const float v = __half2float(__ushort_as_half((unsigned short)(P >> 16)));
#pragma unroll
            for (int k = 0; k < 8; ++k)
                acc[k] = fmaf(v, bf2f((unsigned short)xv[k]), acc[k]);
        }
    }

    // reduce across the 8 edge-slot groups (lane bits 3,4,5)
#pragma unroll
    for (int k = 0; k < 8; ++k) {
        acc[k] += __shfl_xor(acc[k], 8, 64);
        acc[k] += __shfl_xor(acc[k], 16, 64);
        acc[k] += __shfl_xor(acc[k], 32, 64);
    }

    if (eslot == 0) {
        const int chb = cg * 8;
        if (LAST) {
            float* op = (float*)xout_ + (size_t)row * OUTCH + chb;
            const floatx4 b0 = *(const floatx4*)(bias + chb);
            const floatx4 b1 = *(const floatx4*)(bias + chb + 4);
            floatx4 o0, o1;
            o0[0] = acc[0] + b0[0]; o0[1] = acc[1] + b0[1];
            o0[2] = acc[2] + b0[2]; o0[3] = acc[3] + b0[3];
            o1[0] = acc[4] + b1[0]; o1[1] = acc[5] + b1[1];
            o1[2] = acc[6] + b1[2]; o1[3] = acc[7] + b1[3];
            __builtin_nontemporal_store(o0, (floatx4*)op);
            __builtin_nontemporal_store(o1, (floatx4*)(op + 4));
        } else {
            unsigned short* op = (unsigned short*)xout_ + (size_t)row * OUTCH + chb;
            short8 o;
#pragma unroll
            for (int k = 0; k < 8; ++k) o[k] = (short)f2bf(acc[k]);
            __builtin_nontemporal_store(o, (short8*)op);
        }
    }
}

extern "C" void kernel_launch(void* const* d_in, const int* in_sizes, int n_in,
                              void* d_out, int out_size, void* d_ws, size_t ws_size,
                              hipStream_t stream) {
    const int*   adj   = (const int*)d_in[0];     // [2, E]
    const float* avals = (const float*)d_in[1];   // [E]
    const float* feat  = (const float*)d_in[2];   // [N, 512]
    const float* W     = (const float*)d_in[3];   // [512, 64]
    const float* bias  = (const float*)d_in[4];   // [64]
    float* out = (float*)d_out;

    const int E_ = in_sizes[1];
    const int* rows = adj;
    const int* cols = adj + E_;

    // workspace layout (16B-aligned segments), total ~22.7 MB
    unsigned short* x0  = (unsigned short*)d_ws;            // N*64 bf16 (6.4 MB)
    unsigned short* x1  = x0 + (size_t)NN * OUTCH;          // N*64 bf16 (6.4 MB)
    unsigned short* Wbf = x1 + (size_t)NN * OUTCH;          // 64*512 bf16 (64 KB)
    unsigned* ell = (unsigned*)(Wbf + (size_t)OUTCH * INCH);// N*MAXD u32 (9.6 MB)
    int* deg = (int*)(ell + (size_t)NN * MAXD);             // N int (200 KB)

    // ---- prep: zero deg + convert W to bf16 [n][k] ----
    prep_kernel<<<128, 256, 0, stream>>>(W, Wbf, deg);

    // ---- fused: dense projection (bf16 MFMA) + ELL scatter (nt stores) ----
    fused_gemm_scatter<<<GB + SB, 256, 0, stream>>>(feat, Wbf, x0, rows, cols, avals,
                                                    deg, ell, E_);

    // ---- two SpMM hops; bias fused into the last ----
    spmm_full<false><<<NN / 4, 256, 0, stream>>>(deg, ell, x0, x1, nullptr);
    spmm_full<true><<<NN / 4, 256, 0, stream>>>(deg, ell, x1, out, bias);
}